// Round 2
// baseline (439.936 us; speedup 1.0000x reference)
//
#include <hip/hip_runtime.h>
#include <hip/hip_bf16.h>

#define NN 50000
#define EE 800000
#define DD 128

typedef __attribute__((ext_vector_type(8))) short bf8v;   // 8 bf16 (4 VGPR)
typedef __attribute__((ext_vector_type(4))) float f4v;    // 4 f32

static __device__ __forceinline__ short f2bf(float f) {
    union { float f; unsigned int u; } v; v.f = f;
    unsigned int u = v.u;
    u += 0x7fffu + ((u >> 16) & 1u);   // RNE
    return (short)(u >> 16);
}

static __device__ __forceinline__ bf8v pack8(f4v a, f4v b) {
    bf8v r;
    r[0] = f2bf(a[0]); r[1] = f2bf(a[1]); r[2] = f2bf(a[2]); r[3] = f2bf(a[3]);
    r[4] = f2bf(b[0]); r[5] = f2bf(b[1]); r[6] = f2bf(b[2]); r[7] = f2bf(b[3]);
    return r;
}

// Repack fp32 row-major W[K][128] into MFMA B-fragment layout.
__global__ __launch_bounds__(256) void make_frags(const float* __restrict__ W,
                                                  short* __restrict__ out, int total) {
    int idx = blockIdx.x * 256 + threadIdx.x;
    if (idx >= total) return;
    int e    = idx & 7;
    int lane = (idx >> 3) & 63;
    int ntg  = (idx >> 9) & 7;
    int kc   = idx >> 12;
    int k = kc * 32 + (lane >> 4) * 8 + e;
    int n = ntg * 16 + (lane & 15);
    out[idx] = f2bf(W[k * DD + n]);
}

// ---------------- counting sort by destination row ----------------
__global__ __launch_bounds__(256) void hist_kernel(const int* __restrict__ ei,
                                                   int* __restrict__ cnt) {
    int e = blockIdx.x * 256 + threadIdx.x;
    if (e < EE) atomicAdd(&cnt[ei[e]], 1);
}

__global__ __launch_bounds__(1024) void scan_kernel(const int* __restrict__ cnt,
                                                    int* __restrict__ cursor) {
    __shared__ int part[1024];
    int t = threadIdx.x;
    const int C = (NN + 1023) / 1024;   // 49
    int base = t * C;
    int s = 0;
    for (int i = 0; i < C; ++i) { int idx = base + i; if (idx < NN) s += cnt[idx]; }
    part[t] = s;
    __syncthreads();
    for (int off = 1; off < 1024; off <<= 1) {
        int v = (t >= off) ? part[t - off] : 0;
        __syncthreads();
        part[t] += v;
        __syncthreads();
    }
    int run = (t == 0) ? 0 : part[t - 1];   // exclusive prefix
    for (int i = 0; i < C; ++i) {
        int idx = base + i;
        if (idx < NN) { cursor[idx] = run; run += cnt[idx]; }
    }
}

__global__ __launch_bounds__(256) void scatter_kernel(const int* __restrict__ ei,
                                                      int* __restrict__ cursor,
                                                      int* __restrict__ srt) {
    int e = blockIdx.x * 256 + threadIdx.x;
    if (e < EE) {
        int r = ei[e], c = ei[EE + e];
        int pos = atomicAdd(&cursor[r], 1);
        srt[pos] = r;
        srt[EE + pos] = c;
    }
}

// ---------------- edge kernel: message MLP + segmented scatter-add ----------------
__global__ __launch_bounds__(256) void edge_kernel(
    const float* __restrict__ x, const int* __restrict__ srt,
    const short* __restrict__ W1f, const short* __restrict__ W2f,
    const float* __restrict__ bm1, const float* __restrict__ bm2,
    float* __restrict__ aggr)
{
    __shared__ char smem[64 * 256 * 2 + 64 * 128 * 2 + 256];
    char* As = smem;                       // [64][256] bf16 swizzled; reused as Y [64][128] f32
    char* Hs = smem + 64 * 256 * 2;        // [64][128] bf16, XOR-swizzled
    int* rows_s = (int*)(smem + 64 * 256 * 2 + 64 * 128 * 2);

    const int tid = threadIdx.x;
    const int w = tid >> 6, lane = tid & 63;

    // ---- stage A: gather x[row]||x[col] -> bf16 LDS (edges dest-sorted) ----
    {
        int eloc = tid >> 2, s = tid & 3;
        int eg = blockIdx.x * 64 + eloc;
        int r = srt[eg];
        int c = srt[EE + eg];
        if (s == 0) rows_s[eloc] = r;
        const float* xr = x + (size_t)r * DD + s * 32;
        const float* xc = x + (size_t)c * DD + s * 32;
        int swz = (eloc & 7) << 4;
        #pragma unroll
        for (int i2 = 0; i2 < 4; ++i2) {
            f4v a0 = *(const f4v*)(xr + i2 * 8);
            f4v a1 = *(const f4v*)(xr + i2 * 8 + 4);
            int addr = eloc * 512 + s * 64 + i2 * 16;
            *(bf8v*)(As + (addr ^ swz)) = pack8(a0, a1);
            f4v b0 = *(const f4v*)(xc + i2 * 8);
            f4v b1 = *(const f4v*)(xc + i2 * 8 + 4);
            int addr2 = eloc * 512 + 256 + s * 64 + i2 * 16;
            *(bf8v*)(As + (addr2 ^ swz)) = pack8(b0, b1);
        }
    }

    // ---- weight fragments into registers (per-wave 32-col slice) ----
    bf8v w1f[8][2], w2f[4][2];
    #pragma unroll
    for (int kc = 0; kc < 8; ++kc)
        #pragma unroll
        for (int nt = 0; nt < 2; ++nt)
            w1f[kc][nt] = *(const bf8v*)(W1f + (((kc * 8) + (w * 2 + nt)) * 64 + lane) * 8);
    #pragma unroll
    for (int kc = 0; kc < 4; ++kc)
        #pragma unroll
        for (int nt = 0; nt < 2; ++nt)
            w2f[kc][nt] = *(const bf8v*)(W2f + (((kc * 8) + (w * 2 + nt)) * 64 + lane) * 8);

    __syncthreads();

    // ---- GEMM1: [64x256] @ [256x32-slice] ----
    f4v acc[4][2];
    #pragma unroll
    for (int mt = 0; mt < 4; ++mt)
        #pragma unroll
        for (int nt = 0; nt < 2; ++nt)
            acc[mt][nt] = (f4v){0.f, 0.f, 0.f, 0.f};
    #pragma unroll
    for (int kc = 0; kc < 8; ++kc) {
        bf8v a[4];
        int kb = kc * 64 + (lane >> 4) * 16;
        #pragma unroll
        for (int mt = 0; mt < 4; ++mt) {
            int row = mt * 16 + (lane & 15);
            a[mt] = *(const bf8v*)(As + ((row * 512 + kb) ^ ((row & 7) << 4)));
        }
        #pragma unroll
        for (int mt = 0; mt < 4; ++mt)
            #pragma unroll
            for (int nt = 0; nt < 2; ++nt)
                acc[mt][nt] = __builtin_amdgcn_mfma_f32_16x16x32_bf16(a[mt], w1f[kc][nt], acc[mt][nt], 0, 0, 0);
    }

    // ---- bias + SiLU -> Hs (bf16, swizzled) ----
    int col0 = w * 32 + (lane & 15);
    float b1a = bm1[col0], b1b = bm1[col0 + 16];
    #pragma unroll
    for (int mt = 0; mt < 4; ++mt)
        #pragma unroll
        for (int nt = 0; nt < 2; ++nt) {
            float bb = nt ? b1b : b1a;
            int col = col0 + nt * 16;
            #pragma unroll
            for (int r = 0; r < 4; ++r) {
                float v = acc[mt][nt][r] + bb;
                v = v / (1.f + __expf(-v));     // SiLU
                int row = mt * 16 + (lane >> 4) * 4 + r;
                *(short*)(Hs + ((row * 256 + col * 2) ^ ((row & 7) << 4))) = f2bf(v);
            }
        }
    __syncthreads();    // As dead after this (all waves finished GEMM1)

    // ---- GEMM2: [64x128] @ [128x32-slice] ----
    f4v acc2[4][2];
    #pragma unroll
    for (int mt = 0; mt < 4; ++mt)
        #pragma unroll
        for (int nt = 0; nt < 2; ++nt)
            acc2[mt][nt] = (f4v){0.f, 0.f, 0.f, 0.f};
    #pragma unroll
    for (int kc = 0; kc < 4; ++kc) {
        bf8v a[4];
        int kb = kc * 64 + (lane >> 4) * 16;
        #pragma unroll
        for (int mt = 0; mt < 4; ++mt) {
            int row = mt * 16 + (lane & 15);
            a[mt] = *(const bf8v*)(Hs + ((row * 256 + kb) ^ ((row & 7) << 4)));
        }
        #pragma unroll
        for (int mt = 0; mt < 4; ++mt)
            #pragma unroll
            for (int nt = 0; nt < 2; ++nt)
                acc2[mt][nt] = __builtin_amdgcn_mfma_f32_16x16x32_bf16(a[mt], w2f[kc][nt], acc2[mt][nt], 0, 0, 0);
    }

    // ---- bias, park messages as f32 in As [64][128] (swizzled) ----
    float b2a = bm2[col0], b2b = bm2[col0 + 16];
    #pragma unroll
    for (int mt = 0; mt < 4; ++mt)
        #pragma unroll
        for (int nt = 0; nt < 2; ++nt) {
            int col = col0 + nt * 16;
            float bb = nt ? b2b : b2a;
            #pragma unroll
            for (int r = 0; r < 4; ++r) {
                int rowl = mt * 16 + (lane >> 4) * 4 + r;
                *(float*)(As + ((rowl * 512 + col * 4) ^ ((rowl & 7) << 4))) = acc2[mt][nt][r] + bb;
            }
        }
    __syncthreads();

    // ---- segmented reduce over sorted dests: one atomic per (run, col) ----
    if (tid < 128) {
        int col = tid;
        int cur = rows_s[0];
        float run = 0.f;
        for (int row = 0; row < 64; ++row) {
            int d = rows_s[row];                     // uniform across lanes
            float v = *(const float*)(As + ((row * 512 + col * 4) ^ ((row & 7) << 4)));
            if (d != cur) {                          // wave-uniform branch
                unsafeAtomicAdd(aggr + (size_t)cur * DD + col, run);
                run = 0.f; cur = d;
            }
            run += v;
        }
        unsafeAtomicAdd(aggr + (size_t)cur * DD + col, run);
    }
}

// ---------------- node kernel: update MLP + residual + LayerNorm ----------------
__global__ __launch_bounds__(256) void node_kernel(
    const float* __restrict__ x, const float* __restrict__ aggr,
    const short* __restrict__ U1f, const short* __restrict__ U2f,
    const float* __restrict__ bu1, const float* __restrict__ bu2,
    const float* __restrict__ gmm, const float* __restrict__ bta,
    float* __restrict__ out)
{
    __shared__ char smem[64 * 256 * 2 + 64 * 128 * 2];
    char* As = smem;                    // [64][256] bf16 swizzled; later reused as Ys [64][128] f32
    char* Hs = smem + 64 * 256 * 2;     // [64][128] bf16 swizzled; later reused as LN partials

    const int tid = threadIdx.x;
    const int w = tid >> 6, lane = tid & 63;
    const int rbase = blockIdx.x * 64;

    {
        int rloc = tid >> 2, s = tid & 3;
        int rg = rbase + rloc;
        int rgc = rg < NN ? rg : 0;
        const float* xr = x + (size_t)rgc * DD + s * 32;
        const float* ar = aggr + (size_t)rgc * DD + s * 32;
        int swz = (rloc & 7) << 4;
        #pragma unroll
        for (int i2 = 0; i2 < 4; ++i2) {
            f4v a0 = *(const f4v*)(xr + i2 * 8);
            f4v a1 = *(const f4v*)(xr + i2 * 8 + 4);
            int addr = rloc * 512 + s * 64 + i2 * 16;
            *(bf8v*)(As + (addr ^ swz)) = pack8(a0, a1);
            f4v b0 = *(const f4v*)(ar + i2 * 8);
            f4v b1 = *(const f4v*)(ar + i2 * 8 + 4);
            int addr2 = rloc * 512 + 256 + s * 64 + i2 * 16;
            *(bf8v*)(As + (addr2 ^ swz)) = pack8(b0, b1);
        }
    }

    bf8v u1f[8][2], u2f[4][2];
    #pragma unroll
    for (int kc = 0; kc < 8; ++kc)
        #pragma unroll
        for (int nt = 0; nt < 2; ++nt)
            u1f[kc][nt] = *(const bf8v*)(U1f + (((kc * 8) + (w * 2 + nt)) * 64 + lane) * 8);
    #pragma unroll
    for (int kc = 0; kc < 4; ++kc)
        #pragma unroll
        for (int nt = 0; nt < 2; ++nt)
            u2f[kc][nt] = *(const bf8v*)(U2f + (((kc * 8) + (w * 2 + nt)) * 64 + lane) * 8);

    __syncthreads();

    f4v acc[4][2];
    #pragma unroll
    for (int mt = 0; mt < 4; ++mt)
        #pragma unroll
        for (int nt = 0; nt < 2; ++nt)
            acc[mt][nt] = (f4v){0.f, 0.f, 0.f, 0.f};
    #pragma unroll
    for (int kc = 0; kc < 8; ++kc) {
        bf8v a[4];
        int kb = kc * 64 + (lane >> 4) * 16;
        #pragma unroll
        for (int mt = 0; mt < 4; ++mt) {
            int row = mt * 16 + (lane & 15);
            a[mt] = *(const bf8v*)(As + ((row * 512 + kb) ^ ((row & 7) << 4)));
        }
        #pragma unroll
        for (int mt = 0; mt < 4; ++mt)
            #pragma unroll
            for (int nt = 0; nt < 2; ++nt)
                acc[mt][nt] = __builtin_amdgcn_mfma_f32_16x16x32_bf16(a[mt], u1f[kc][nt], acc[mt][nt], 0, 0, 0);
    }

    int col0 = w * 32 + (lane & 15);
    float b1a = bu1[col0], b1b = bu1[col0 + 16];
    #pragma unroll
    for (int mt = 0; mt < 4; ++mt)
        #pragma unroll
        for (int nt = 0; nt < 2; ++nt) {
            float bb = nt ? b1b : b1a;
            int col = col0 + nt * 16;
            #pragma unroll
            for (int r = 0; r < 4; ++r) {
                float v = acc[mt][nt][r] + bb;
                v = v / (1.f + __expf(-v));
                int row = mt * 16 + (lane >> 4) * 4 + r;
                *(short*)(Hs + ((row * 256 + col * 2) ^ ((row & 7) << 4))) = f2bf(v);
            }
        }
    __syncthreads();

    f4v acc2[4][2];
    #pragma unroll
    for (int mt = 0; mt < 4; ++mt)
        #pragma unroll
        for (int nt = 0; nt < 2; ++nt)
            acc2[mt][nt] = (f4v){0.f, 0.f, 0.f, 0.f};
    #pragma unroll
    for (int kc = 0; kc < 4; ++kc) {
        bf8v a[4];
        int kb = kc * 64 + (lane >> 4) * 16;
        #pragma unroll
        for (int mt = 0; mt < 4; ++mt) {
            int row = mt * 16 + (lane & 15);
            a[mt] = *(const bf8v*)(Hs + ((row * 256 + kb) ^ ((row & 7) << 4)));
        }
        #pragma unroll
        for (int mt = 0; mt < 4; ++mt)
            #pragma unroll
            for (int nt = 0; nt < 2; ++nt)
                acc2[mt][nt] = __builtin_amdgcn_mfma_f32_16x16x32_bf16(a[mt], u2f[kc][nt], acc2[mt][nt], 0, 0, 0);
    }

    float b2a = bu2[col0], b2b = bu2[col0 + 16];
    #pragma unroll
    for (int mt = 0; mt < 4; ++mt)
        #pragma unroll
        for (int nt = 0; nt < 2; ++nt) {
            int col = col0 + nt * 16;
            float bb = nt ? b2b : b2a;
            #pragma unroll
            for (int r = 0; r < 4; ++r) {
                int rowl = mt * 16 + (lane >> 4) * 4 + r;
                int rg = rbase + rowl;
                int rgc = rg < NN ? rg : 0;
                float xv = x[(size_t)rgc * DD + col];
                float y = acc2[mt][nt][r] + bb + xv;
                *(float*)(As + ((rowl * 512 + col * 4) ^ ((rowl & 7) << 4))) = y;
            }
        }
    __syncthreads();

    float* ps  = (float*)Hs;        // [64][4]
    float* ps2 = ps + 256;          // [64][4]
    {
        int rloc = tid >> 2, q = tid & 3;
        float s1 = 0.f, s2 = 0.f;
        #pragma unroll
        for (int i = 0; i < 8; ++i) {
            f4v v = *(const f4v*)(As + ((rloc * 512 + q * 128 + i * 16) ^ ((rloc & 7) << 4)));
            s1 += v[0] + v[1] + v[2] + v[3];
            s2 += v[0] * v[0] + v[1] * v[1] + v[2] * v[2] + v[3] * v[3];
        }
        ps[rloc * 4 + q] = s1;
        ps2[rloc * 4 + q] = s2;
    }
    __syncthreads();
    {
        int rloc = tid >> 2, q = tid & 3;
        float fs  = ps[rloc * 4] + ps[rloc * 4 + 1] + ps[rloc * 4 + 2] + ps[rloc * 4 + 3];
        float fs2 = ps2[rloc * 4] + ps2[rloc * 4 + 1] + ps2[rloc * 4 + 2] + ps2[rloc * 4 + 3];
        float mu  = fs * (1.f / 128.f);
        float var = fs2 * (1.f / 128.f) - mu * mu;
        float inv = rsqrtf(var + 1e-5f);
        int rg = rbase + rloc;
        if (rg < NN) {
            #pragma unroll
            for (int i = 0; i < 8; ++i) {
                int col = q * 32 + i * 4;
                f4v v  = *(const f4v*)(As + ((rloc * 512 + col * 4) ^ ((rloc & 7) << 4)));
                f4v gg = *(const f4v*)(gmm + col);
                f4v bb = *(const f4v*)(bta + col);
                f4v o;
                #pragma unroll
                for (int j = 0; j < 4; ++j)
                    o[j] = (v[j] - mu) * inv * gg[j] + bb[j];
                *(f4v*)(out + (size_t)rg * DD + col) = o;
            }
        }
    }
}

extern "C" void kernel_launch(void* const* d_in, const int* in_sizes, int n_in,
                              void* d_out, int out_size, void* d_ws, size_t ws_size,
                              hipStream_t stream) {
    const float* x    = (const float*)d_in[0];
    const int*   ei   = (const int*)d_in[1];
    const float* wm1  = (const float*)d_in[2];
    const float* bm1  = (const float*)d_in[3];
    const float* wm2  = (const float*)d_in[4];
    const float* bm2  = (const float*)d_in[5];
    const float* wu1  = (const float*)d_in[6];
    const float* bu1  = (const float*)d_in[7];
    const float* wu2  = (const float*)d_in[8];
    const float* bu2  = (const float*)d_in[9];
    const float* gmm  = (const float*)d_in[10];
    const float* bta  = (const float*)d_in[11];
    float* out = (float*)d_out;

    const size_t w1fb = 8 * 8 * 64 * 8 * 2;                      // 65536 B
    const size_t w2fb = 4 * 8 * 64 * 8 * 2;                      // 32768 B
    const size_t frags_b  = 2 * (w1fb + w2fb);                   // 196608 B
    const size_t cnt_b    = (size_t)NN * 4;                      // 200000 B
    const size_t cursor_b = (size_t)NN * 4;                      // 200000 B
    const size_t srt_b    = (size_t)2 * EE * 4;                  // 6.4 MB
    const size_t aggr_b   = (size_t)NN * DD * 4;                 // 25.6 MB
    const size_t need_sort = frags_b + cnt_b + cursor_b + srt_b; // ~7 MB
    const size_t need_all  = need_sort + aggr_b;                 // ~32.6 MB

    char* wsB = (char*)d_ws;
    short* W1f = (short*)wsB;
    short* W2f = (short*)(wsB + w1fb);
    short* U1f = (short*)(wsB + w1fb + w2fb);
    short* U2f = (short*)(wsB + w1fb + w2fb + w1fb);

    bool do_sort = ws_size >= need_sort;
    int*   cnt    = (int*)(wsB + frags_b);
    int*   cursor = (int*)(wsB + frags_b + cnt_b);
    int*   srt    = (int*)(wsB + frags_b + cnt_b + cursor_b);
    float* aggr   = (ws_size >= need_all) ? (float*)(wsB + need_sort) : (float*)d_out;

    make_frags<<<128, 256, 0, stream>>>(wm1, W1f, 8 * 4096);
    make_frags<<<64, 256, 0, stream>>>(wm2, W2f, 4 * 4096);
    make_frags<<<128, 256, 0, stream>>>(wu1, U1f, 8 * 4096);
    make_frags<<<64, 256, 0, stream>>>(wu2, U2f, 4 * 4096);
    hipMemsetAsync(aggr, 0, aggr_b, stream);

    const int* edges_for_kernel;
    if (do_sort) {
        hipMemsetAsync(cnt, 0, cnt_b, stream);
        hist_kernel<<<(EE + 255) / 256, 256, 0, stream>>>(ei, cnt);
        scan_kernel<<<1, 1024, 0, stream>>>(cnt, cursor);
        scatter_kernel<<<(EE + 255) / 256, 256, 0, stream>>>(ei, cursor, srt);
        edges_for_kernel = srt;
    } else {
        edges_for_kernel = ei;   // unsorted fallback: epilogue still correct
    }

    edge_kernel<<<EE / 64, 256, 0, stream>>>(x, edges_for_kernel, W1f, W2f, bm1, bm2, aggr);
    node_kernel<<<(NN + 63) / 64, 256, 0, stream>>>(x, aggr, U1f, U2f, bu1, bu2, gmm, bta, out);
}

// Round 3
// 348.864 us; speedup vs baseline: 1.2611x; 1.2611x over previous
//
#include <hip/hip_runtime.h>
#include <hip/hip_bf16.h>

#define NN 50000
#define EE 800000
#define DD 128

typedef __attribute__((ext_vector_type(8))) short bf8v;        // 8 bf16 (4 VGPR)
typedef __attribute__((ext_vector_type(4))) float f4v;         // 4 f32
typedef __attribute__((ext_vector_type(4))) unsigned int u4v;  // 16B

static __device__ __forceinline__ unsigned int bpack2(float lo, float hi) {
    union { __hip_bfloat162 h2; unsigned int u; } c;
    c.h2 = __float22bfloat162_rn(float2{lo, hi});   // v_cvt_pk_bf16_f32
    return c.u;
}

static __device__ __forceinline__ u4v pack8(f4v a, f4v b) {
    u4v r;
    r[0] = bpack2(a[0], a[1]); r[1] = bpack2(a[2], a[3]);
    r[2] = bpack2(b[0], b[1]); r[3] = bpack2(b[2], b[3]);
    return r;
}

static __device__ __forceinline__ short f2bf_s(float f) {
    union { __hip_bfloat16 h; short s; } c;
    c.h = __float2bfloat16(f);
    return c.s;
}

static __device__ __forceinline__ float silu(float v) {
    return v * __builtin_amdgcn_rcpf(1.f + __expf(-v));
}

// Repack fp32 row-major W[K][128] into MFMA B-fragment layout.
__global__ __launch_bounds__(256) void make_frags(const float* __restrict__ W,
                                                  short* __restrict__ out, int total) {
    int idx = blockIdx.x * 256 + threadIdx.x;
    if (idx >= total) return;
    int e    = idx & 7;
    int lane = (idx >> 3) & 63;
    int ntg  = (idx >> 9) & 7;
    int kc   = idx >> 12;
    int k = kc * 32 + (lane >> 4) * 8 + e;
    int n = ntg * 16 + (lane & 15);
    out[idx] = f2bf_s(W[k * DD + n]);
}

// ---------------- counting sort by destination row (rank-based, scatter atomic-free) ----
__global__ __launch_bounds__(256) void hist_rank_kernel(const int* __restrict__ ei,
                                                        int* __restrict__ cnt,
                                                        int* __restrict__ rank) {
    int e = blockIdx.x * 256 + threadIdx.x;
    if (e < EE) rank[e] = atomicAdd(&cnt[ei[e]], 1);
}

__global__ __launch_bounds__(1024) void scan_kernel(const int* __restrict__ cnt,
                                                    int* __restrict__ cursor) {
    __shared__ int part[1024];
    int t = threadIdx.x;
    const int C = (NN + 1023) / 1024;   // 49
    int base = t * C;
    int s = 0;
    for (int i = 0; i < C; ++i) { int idx = base + i; if (idx < NN) s += cnt[idx]; }
    part[t] = s;
    __syncthreads();
    for (int off = 1; off < 1024; off <<= 1) {
        int v = (t >= off) ? part[t - off] : 0;
        __syncthreads();
        part[t] += v;
        __syncthreads();
    }
    int run = (t == 0) ? 0 : part[t - 1];   // exclusive prefix
    for (int i = 0; i < C; ++i) {
        int idx = base + i;
        if (idx < NN) { cursor[idx] = run; run += cnt[idx]; }
    }
}

__global__ __launch_bounds__(256) void scatter_kernel(const int* __restrict__ ei,
                                                      const int* __restrict__ cursor,
                                                      const int* __restrict__ rank,
                                                      int2* __restrict__ srt2) {
    int e = blockIdx.x * 256 + threadIdx.x;
    if (e < EE) {
        int r = ei[e];
        int pos = cursor[r] + rank[e];
        srt2[pos] = make_int2(r, ei[EE + e]);
    }
}

// ---------------- edge kernel: message MLP + segmented scatter-add ----------------
// LDS: As 32KB (A-tile bf16; reused for H bf16; reused for msg f32) + rows 256B
__global__ __launch_bounds__(256, 4) void edge_kernel(
    const float* __restrict__ x, const int2* __restrict__ srt2,
    const int* __restrict__ ei, int use_pairs,
    const short* __restrict__ W1f, const short* __restrict__ W2f,
    const float* __restrict__ bm1, const float* __restrict__ bm2,
    float* __restrict__ aggr)
{
    __shared__ char smem[64 * 512 + 256];
    char* As = smem;                       // [64][256] bf16 swizzled / H [64][128] bf16 / msg [64][128] f32
    int* rows_s = (int*)(smem + 64 * 512);

    const int tid = threadIdx.x;
    const int w = tid >> 6, lane = tid & 63;

    // ---- stage A: gather x[row]||x[col] -> bf16 LDS (edges dest-sorted) ----
    {
        int eloc = tid >> 2, s = tid & 3;
        int eg = blockIdx.x * 64 + eloc;
        int r, c;
        if (use_pairs) { int2 rc = srt2[eg]; r = rc.x; c = rc.y; }
        else           { r = ei[eg]; c = ei[EE + eg]; }
        if (s == 0) rows_s[eloc] = r;
        const float* xr = x + (size_t)r * DD + s * 32;
        const float* xc = x + (size_t)c * DD + s * 32;
        int swz = (eloc & 7) << 4;
        #pragma unroll
        for (int i2 = 0; i2 < 4; ++i2) {
            f4v a0 = *(const f4v*)(xr + i2 * 8);
            f4v a1 = *(const f4v*)(xr + i2 * 8 + 4);
            int addr = eloc * 512 + s * 64 + i2 * 16;
            *(u4v*)(As + (addr ^ swz)) = pack8(a0, a1);
            f4v b0 = *(const f4v*)(xc + i2 * 8);
            f4v b1 = *(const f4v*)(xc + i2 * 8 + 4);
            int addr2 = eloc * 512 + 256 + s * 64 + i2 * 16;
            *(u4v*)(As + (addr2 ^ swz)) = pack8(b0, b1);
        }
    }

    // ---- weight fragments into registers (per-wave 32-col slice) ----
    bf8v w1f[8][2], w2f[4][2];
    #pragma unroll
    for (int kc = 0; kc < 8; ++kc)
        #pragma unroll
        for (int nt = 0; nt < 2; ++nt)
            w1f[kc][nt] = *(const bf8v*)(W1f + (((kc * 8) + (w * 2 + nt)) * 64 + lane) * 8);
    #pragma unroll
    for (int kc = 0; kc < 4; ++kc)
        #pragma unroll
        for (int nt = 0; nt < 2; ++nt)
            w2f[kc][nt] = *(const bf8v*)(W2f + (((kc * 8) + (w * 2 + nt)) * 64 + lane) * 8);

    __syncthreads();

    // ---- GEMM1: [64x256] @ [256x32-slice] ----
    f4v acc[4][2];
    #pragma unroll
    for (int mt = 0; mt < 4; ++mt)
        #pragma unroll
        for (int nt = 0; nt < 2; ++nt)
            acc[mt][nt] = (f4v){0.f, 0.f, 0.f, 0.f};
    #pragma unroll
    for (int kc = 0; kc < 8; ++kc) {
        bf8v a[4];
        int kb = kc * 64 + (lane >> 4) * 16;
        #pragma unroll
        for (int mt = 0; mt < 4; ++mt) {
            int row = mt * 16 + (lane & 15);
            a[mt] = *(const bf8v*)(As + ((row * 512 + kb) ^ ((row & 7) << 4)));
        }
        #pragma unroll
        for (int mt = 0; mt < 4; ++mt)
            #pragma unroll
            for (int nt = 0; nt < 2; ++nt)
                acc[mt][nt] = __builtin_amdgcn_mfma_f32_16x16x32_bf16(a[mt], w1f[kc][nt], acc[mt][nt], 0, 0, 0);
    }
    __syncthreads();   // all waves done reading A-tile; As reusable

    // ---- bias + SiLU -> H overlaying As (bf16, swizzled, 16KB) ----
    int col0 = w * 32 + (lane & 15);
    float b1a = bm1[col0], b1b = bm1[col0 + 16];
    #pragma unroll
    for (int mt = 0; mt < 4; ++mt)
        #pragma unroll
        for (int nt = 0; nt < 2; ++nt) {
            float bb = nt ? b1b : b1a;
            int col = col0 + nt * 16;
            #pragma unroll
            for (int r = 0; r < 4; ++r) {
                float v = silu(acc[mt][nt][r] + bb);
                int row = mt * 16 + (lane >> 4) * 4 + r;
                *(short*)(As + ((row * 256 + col * 2) ^ ((row & 7) << 4))) = f2bf_s(v);
            }
        }
    __syncthreads();

    // ---- GEMM2: [64x128] @ [128x32-slice] ----
    f4v acc2[4][2];
    #pragma unroll
    for (int mt = 0; mt < 4; ++mt)
        #pragma unroll
        for (int nt = 0; nt < 2; ++nt)
            acc2[mt][nt] = (f4v){0.f, 0.f, 0.f, 0.f};
    #pragma unroll
    for (int kc = 0; kc < 4; ++kc) {
        bf8v a[4];
        int kb = kc * 64 + (lane >> 4) * 16;
        #pragma unroll
        for (int mt = 0; mt < 4; ++mt) {
            int row = mt * 16 + (lane & 15);
            a[mt] = *(const bf8v*)(As + ((row * 256 + kb) ^ ((row & 7) << 4)));
        }
        #pragma unroll
        for (int mt = 0; mt < 4; ++mt)
            #pragma unroll
            for (int nt = 0; nt < 2; ++nt)
                acc2[mt][nt] = __builtin_amdgcn_mfma_f32_16x16x32_bf16(a[mt], w2f[kc][nt], acc2[mt][nt], 0, 0, 0);
    }
    __syncthreads();   // all waves done reading H; As reusable

    // ---- bias, park messages as f32 in As [64][128] (swizzled, 32KB) ----
    float b2a = bm2[col0], b2b = bm2[col0 + 16];
    #pragma unroll
    for (int mt = 0; mt < 4; ++mt)
        #pragma unroll
        for (int nt = 0; nt < 2; ++nt) {
            int col = col0 + nt * 16;
            float bb = nt ? b2b : b2a;
            #pragma unroll
            for (int r = 0; r < 4; ++r) {
                int rowl = mt * 16 + (lane >> 4) * 4 + r;
                *(float*)(As + ((rowl * 512 + col * 4) ^ ((rowl & 7) << 4))) = acc2[mt][nt][r] + bb;
            }
        }
    __syncthreads();

    // ---- segmented reduce over sorted dests: all 256 threads, 32 rows each ----
    {
        int col = tid & 127;
        int r0 = (tid >> 7) * 32;
        int cur = rows_s[r0];
        float run = 0.f;
        for (int i = 0; i < 32; ++i) {
            int row = r0 + i;
            int d = rows_s[row];                     // uniform across lanes
            float v = *(const float*)(As + ((row * 512 + col * 4) ^ ((row & 7) << 4)));
            if (d != cur) {                          // wave-uniform branch
                unsafeAtomicAdd(aggr + (size_t)cur * DD + col, run);
                run = 0.f; cur = d;
            }
            run += v;
        }
        unsafeAtomicAdd(aggr + (size_t)cur * DD + col, run);
    }
}

// ---------------- node kernel: update MLP + residual + LayerNorm ----------------
// LDS: As 32KB (A-tile / H / Y-f32) + 2KB LN partials
__global__ __launch_bounds__(256, 4) void node_kernel(
    const float* __restrict__ x, const float* __restrict__ aggr,
    const short* __restrict__ U1f, const short* __restrict__ U2f,
    const float* __restrict__ bu1, const float* __restrict__ bu2,
    const float* __restrict__ gmm, const float* __restrict__ bta,
    float* __restrict__ out)
{
    __shared__ char smem[64 * 512 + 2048];
    char* As = smem;
    float* ps  = (float*)(smem + 64 * 512);        // [64][4]
    float* ps2 = ps + 256;                          // [64][4]

    const int tid = threadIdx.x;
    const int w = tid >> 6, lane = tid & 63;
    const int rbase = blockIdx.x * 64;

    {
        int rloc = tid >> 2, s = tid & 3;
        int rg = rbase + rloc;
        int rgc = rg < NN ? rg : 0;
        const float* xr = x + (size_t)rgc * DD + s * 32;
        const float* ar = aggr + (size_t)rgc * DD + s * 32;
        int swz = (rloc & 7) << 4;
        #pragma unroll
        for (int i2 = 0; i2 < 4; ++i2) {
            f4v a0 = *(const f4v*)(xr + i2 * 8);
            f4v a1 = *(const f4v*)(xr + i2 * 8 + 4);
            int addr = rloc * 512 + s * 64 + i2 * 16;
            *(u4v*)(As + (addr ^ swz)) = pack8(a0, a1);
            f4v b0 = *(const f4v*)(ar + i2 * 8);
            f4v b1 = *(const f4v*)(ar + i2 * 8 + 4);
            int addr2 = rloc * 512 + 256 + s * 64 + i2 * 16;
            *(u4v*)(As + (addr2 ^ swz)) = pack8(b0, b1);
        }
    }

    bf8v u1f[8][2], u2f[4][2];
    #pragma unroll
    for (int kc = 0; kc < 8; ++kc)
        #pragma unroll
        for (int nt = 0; nt < 2; ++nt)
            u1f[kc][nt] = *(const bf8v*)(U1f + (((kc * 8) + (w * 2 + nt)) * 64 + lane) * 8);
    #pragma unroll
    for (int kc = 0; kc < 4; ++kc)
        #pragma unroll
        for (int nt = 0; nt < 2; ++nt)
            u2f[kc][nt] = *(const bf8v*)(U2f + (((kc * 8) + (w * 2 + nt)) * 64 + lane) * 8);

    __syncthreads();

    f4v acc[4][2];
    #pragma unroll
    for (int mt = 0; mt < 4; ++mt)
        #pragma unroll
        for (int nt = 0; nt < 2; ++nt)
            acc[mt][nt] = (f4v){0.f, 0.f, 0.f, 0.f};
    #pragma unroll
    for (int kc = 0; kc < 8; ++kc) {
        bf8v a[4];
        int kb = kc * 64 + (lane >> 4) * 16;
        #pragma unroll
        for (int mt = 0; mt < 4; ++mt) {
            int row = mt * 16 + (lane & 15);
            a[mt] = *(const bf8v*)(As + ((row * 512 + kb) ^ ((row & 7) << 4)));
        }
        #pragma unroll
        for (int mt = 0; mt < 4; ++mt)
            #pragma unroll
            for (int nt = 0; nt < 2; ++nt)
                acc[mt][nt] = __builtin_amdgcn_mfma_f32_16x16x32_bf16(a[mt], u1f[kc][nt], acc[mt][nt], 0, 0, 0);
    }
    __syncthreads();

    int col0 = w * 32 + (lane & 15);
    float b1a = bu1[col0], b1b = bu1[col0 + 16];
    #pragma unroll
    for (int mt = 0; mt < 4; ++mt)
        #pragma unroll
        for (int nt = 0; nt < 2; ++nt) {
            float bb = nt ? b1b : b1a;
            int col = col0 + nt * 16;
            #pragma unroll
            for (int r = 0; r < 4; ++r) {
                float v = silu(acc[mt][nt][r] + bb);
                int row = mt * 16 + (lane >> 4) * 4 + r;
                *(short*)(As + ((row * 256 + col * 2) ^ ((row & 7) << 4))) = f2bf_s(v);
            }
        }
    __syncthreads();

    f4v acc2[4][2];
    #pragma unroll
    for (int mt = 0; mt < 4; ++mt)
        #pragma unroll
        for (int nt = 0; nt < 2; ++nt)
            acc2[mt][nt] = (f4v){0.f, 0.f, 0.f, 0.f};
    #pragma unroll
    for (int kc = 0; kc < 4; ++kc) {
        bf8v a[4];
        int kb = kc * 64 + (lane >> 4) * 16;
        #pragma unroll
        for (int mt = 0; mt < 4; ++mt) {
            int row = mt * 16 + (lane & 15);
            a[mt] = *(const bf8v*)(As + ((row * 256 + kb) ^ ((row & 7) << 4)));
        }
        #pragma unroll
        for (int mt = 0; mt < 4; ++mt)
            #pragma unroll
            for (int nt = 0; nt < 2; ++nt)
                acc2[mt][nt] = __builtin_amdgcn_mfma_f32_16x16x32_bf16(a[mt], u2f[kc][nt], acc2[mt][nt], 0, 0, 0);
    }
    __syncthreads();   // all waves done reading H

    float b2a = bu2[col0], b2b = bu2[col0 + 16];
    #pragma unroll
    for (int mt = 0; mt < 4; ++mt)
        #pragma unroll
        for (int nt = 0; nt < 2; ++nt) {
            int col = col0 + nt * 16;
            float bb = nt ? b2b : b2a;
            #pragma unroll
            for (int r = 0; r < 4; ++r) {
                int rowl = mt * 16 + (lane >> 4) * 4 + r;
                int rg = rbase + rowl;
                int rgc = rg < NN ? rg : 0;
                float xv = x[(size_t)rgc * DD + col];
                float y = acc2[mt][nt][r] + bb + xv;
                *(float*)(As + ((rowl * 512 + col * 4) ^ ((rowl & 7) << 4))) = y;
            }
        }
    __syncthreads();

    {
        int rloc = tid >> 2, q = tid & 3;
        float s1 = 0.f, s2 = 0.f;
        #pragma unroll
        for (int i = 0; i < 8; ++i) {
            f4v v = *(const f4v*)(As + ((rloc * 512 + q * 128 + i * 16) ^ ((rloc & 7) << 4)));
            s1 += v[0] + v[1] + v[2] + v[3];
            s2 += v[0] * v[0] + v[1] * v[1] + v[2] * v[2] + v[3] * v[3];
        }
        ps[rloc * 4 + q] = s1;
        ps2[rloc * 4 + q] = s2;
    }
    __syncthreads();
    {
        int rloc = tid >> 2, q = tid & 3;
        float fs  = ps[rloc * 4] + ps[rloc * 4 + 1] + ps[rloc * 4 + 2] + ps[rloc * 4 + 3];
        float fs2 = ps2[rloc * 4] + ps2[rloc * 4 + 1] + ps2[rloc * 4 + 2] + ps2[rloc * 4 + 3];
        float mu  = fs * (1.f / 128.f);
        float var = fs2 * (1.f / 128.f) - mu * mu;
        float inv = rsqrtf(var + 1e-5f);
        int rg = rbase + rloc;
        if (rg < NN) {
            #pragma unroll
            for (int i = 0; i < 8; ++i) {
                int col = q * 32 + i * 4;
                f4v v  = *(const f4v*)(As + ((rloc * 512 + col * 4) ^ ((rloc & 7) << 4)));
                f4v gg = *(const f4v*)(gmm + col);
                f4v bb = *(const f4v*)(bta + col);
                f4v o;
                #pragma unroll
                for (int j = 0; j < 4; ++j)
                    o[j] = (v[j] - mu) * inv * gg[j] + bb[j];
                *(f4v*)(out + (size_t)rg * DD + col) = o;
            }
        }
    }
}

extern "C" void kernel_launch(void* const* d_in, const int* in_sizes, int n_in,
                              void* d_out, int out_size, void* d_ws, size_t ws_size,
                              hipStream_t stream) {
    const float* x    = (const float*)d_in[0];
    const int*   ei   = (const int*)d_in[1];
    const float* wm1  = (const float*)d_in[2];
    const float* bm1  = (const float*)d_in[3];
    const float* wm2  = (const float*)d_in[4];
    const float* bm2  = (const float*)d_in[5];
    const float* wu1  = (const float*)d_in[6];
    const float* bu1  = (const float*)d_in[7];
    const float* wu2  = (const float*)d_in[8];
    const float* bu2  = (const float*)d_in[9];
    const float* gmm  = (const float*)d_in[10];
    const float* bta  = (const float*)d_in[11];
    float* out = (float*)d_out;

    const size_t w1fb    = 8 * 8 * 64 * 8 * 2;                   // 65536 B
    const size_t w2fb    = 4 * 8 * 64 * 8 * 2;                   // 32768 B
    const size_t frags_b = 2 * (w1fb + w2fb);                    // 196608 B
    const size_t cnt_b    = (size_t)NN * 4;                      // 200000 B
    const size_t cursor_b = (size_t)NN * 4;                      // 200000 B
    const size_t rank_b   = (size_t)EE * 4;                      // 3.2 MB
    const size_t srt2_b   = (size_t)EE * 8;                      // 6.4 MB
    const size_t aggr_b   = (size_t)NN * DD * 4;                 // 25.6 MB
    const size_t need_sort = frags_b + cnt_b + cursor_b + rank_b + srt2_b; // ~10.2 MB
    const size_t need_all  = need_sort + aggr_b;                           // ~35.8 MB

    char* wsB = (char*)d_ws;
    short* W1f = (short*)wsB;
    short* W2f = (short*)(wsB + w1fb);
    short* U1f = (short*)(wsB + w1fb + w2fb);
    short* U2f = (short*)(wsB + w1fb + w2fb + w1fb);

    bool do_sort = ws_size >= need_sort;
    int*  cnt    = (int*)(wsB + frags_b);
    int*  cursor = (int*)(wsB + frags_b + cnt_b);
    int*  rank   = (int*)(wsB + frags_b + cnt_b + cursor_b);
    int2* srt2   = (int2*)(wsB + frags_b + cnt_b + cursor_b + rank_b);
    // aggr = d_out fallback is race-free: node block b reads aggr rows [64b,64b+64)
    // (its own rows only) before writing out rows [64b,64b+64).
    float* aggr  = (ws_size >= need_all) ? (float*)(wsB + need_sort) : (float*)d_out;

    make_frags<<<128, 256, 0, stream>>>(wm1, W1f, 8 * 4096);
    make_frags<<<64, 256, 0, stream>>>(wm2, W2f, 4 * 4096);
    make_frags<<<128, 256, 0, stream>>>(wu1, U1f, 8 * 4096);
    make_frags<<<64, 256, 0, stream>>>(wu2, U2f, 4 * 4096);
    hipMemsetAsync(aggr, 0, aggr_b, stream);

    int use_pairs = 0;
    if (do_sort) {
        hipMemsetAsync(cnt, 0, cnt_b, stream);
        hist_rank_kernel<<<(EE + 255) / 256, 256, 0, stream>>>(ei, cnt, rank);
        scan_kernel<<<1, 1024, 0, stream>>>(cnt, cursor);
        scatter_kernel<<<(EE + 255) / 256, 256, 0, stream>>>(ei, cursor, rank, srt2);
        use_pairs = 1;
    }

    edge_kernel<<<EE / 64, 256, 0, stream>>>(x, srt2, ei, use_pairs, W1f, W2f, bm1, bm2, aggr);
    node_kernel<<<(NN + 63) / 64, 256, 0, stream>>>(x, aggr, U1f, U2f, bu1, bu2, gmm, bta, out);
}